// Round 6
// baseline (77.333 us; speedup 1.0000x reference)
//
#include <hip/hip_runtime.h>

#define NS 8192
#define NC 512
#define NF 128

typedef short short8 __attribute__((ext_vector_type(8)));
typedef short short4v __attribute__((ext_vector_type(4)));
typedef float f32x4 __attribute__((ext_vector_type(4)));

static __device__ __forceinline__ unsigned short f2bf(float f) {
    unsigned u = __float_as_uint(f);
    return (unsigned short)((u + 0x7fffu + ((u >> 16) & 1u)) >> 16);   // RNE
}

static __device__ __forceinline__ short8 pack8(const float* p) {
    float4 v0 = *(const float4*)p;
    float4 v1 = *(const float4*)(p + 4);
    short8 o;
    o[0] = (short)f2bf(v0.x); o[1] = (short)f2bf(v0.y);
    o[2] = (short)f2bf(v0.z); o[3] = (short)f2bf(v0.w);
    o[4] = (short)f2bf(v1.x); o[5] = (short)f2bf(v1.y);
    o[6] = (short)f2bf(v1.z); o[7] = (short)f2bf(v1.w);
    return o;
}

// Swizzled short index in a [R][128] bf16 LDS tile:
//   row*128 + (((col>>3) ^ (row&7))<<3) + (col&7)

// One block = 32 samples x ALL 512 centers (4 chunks of 128). 1024 thr = 16 waves.
// wave wv: wg = wv>>3 (sample half / center quad), wf = wv&7 (f-tile / center-tile).
// Single kernel node, exclusive out ownership -> no memset, no atomics.
__global__ __launch_bounds__(1024) void fused1_kernel(const float* __restrict__ X,
                                                      const float* __restrict__ pe,
                                                      const float* __restrict__ centers,
                                                      const float* __restrict__ w,
                                                      float* __restrict__ out) {
    __shared__ __align__(16) short LT[NF * NF];     // 32 KB: L^T, recycled as V chunk
    __shared__ __align__(16) short Ulds[32 * NF];   // 8 KB : U = X@L bf16
    __shared__ __align__(16) short packed[8256];    // 16.5 KB packed tril(pe) bf16
    __shared__ float qxw[8 * 32];
    __shared__ float qcw[8 * NF];
    __shared__ float outw[8 * 32];
    __shared__ float qxfin[32];
    __shared__ float qcfin[NF];

    int t = threadIdx.x;
    int wv = t >> 6, lane = t & 63, g = lane >> 4, r = lane & 15;
    int wg = wv >> 3, wf = wv & 7;
    int swz = r & 7;
    int n0 = blockIdx.x * 32;

    // ---- X A-frags (fp32->bf16 in-register): rows n0 + 16wg + r
    short8 a[4];
#pragma unroll
    for (int kk = 0; kk < 4; ++kk)
        a[kk] = pack8(&X[(size_t)(n0 + 16 * wg + r) * NF + kk * 32 + 8 * g]);
    // ---- weights for this lane's 4 center columns (one per chunk)
    float wl[4];
#pragma unroll
    for (int ch = 0; ch < 4; ++ch) wl[ch] = w[ch * 128 + 16 * wf + r];

    // ---- pe -> packed LDS (coalesced), then scatter to swizzled L^T
    {
        const float4* pe4 = (const float4*)pe;
        for (int c = t; c < 2064; c += 1024) {
            float4 v = pe4[c];
            short4v o;
            o[0] = (short)f2bf(v.x); o[1] = (short)f2bf(v.y);
            o[2] = (short)f2bf(v.z); o[3] = (short)f2bf(v.w);
            ((short4v*)packed)[c] = o;
        }
    }
    __syncthreads();
    for (int idx = t; idx < NF * NF; idx += 1024) {
        int j = idx >> 7, i = idx & 127;            // LT[j][i] = L[i][j]
        short v = (j <= i) ? packed[i * (i + 1) / 2 + j] : (short)0;
        LT[j * NF + (((i >> 3) ^ (j & 7)) << 3) + (i & 7)] = v;
    }
    __syncthreads();

    // ---- B-frags of L^T for f-cols [16wf,16wf+16) (kept in regs; LT freed after)
    short8 bb[4];
    {
        const short8* L8 = (const short8*)LT;
#pragma unroll
        for (int kk = 0; kk < 4; ++kk)
            bb[kk] = L8[(16 * wf + r) * 16 + ((kk * 4 + g) ^ swz)];
    }
    // ---- U = X@L: sample-tile wg, f-tile wf
    f32x4 uacc = (f32x4){0.f, 0.f, 0.f, 0.f};
#pragma unroll
    for (int kk = 0; kk < 4; ++kk)
        uacc = __builtin_amdgcn_mfma_f32_16x16x32_bf16(a[kk], bb[kk], uacc, 0, 0, 0);
#pragma unroll
    for (int reg = 0; reg < 4; ++reg) {
        int row = 16 * wg + 4 * g + reg;            // sample-local row; col = 16wf + r
        int col = 16 * wf + r;
        float x = uacc[reg];
        Ulds[row * NF + (((col >> 3) ^ (row & 7)) << 3) + (col & 7)] = (short)f2bf(x);
        float v = x * x;
        v += __shfl_xor(v, 1); v += __shfl_xor(v, 2);
        v += __shfl_xor(v, 4); v += __shfl_xor(v, 8);
        if (r == 0) qxw[wf * 32 + row] = v;
    }
    __syncthreads();                                 // bb reads done -> LT region free
    if (t < 32) {
        float s = 0.f;
#pragma unroll
        for (int i = 0; i < 8; ++i) s += qxw[i * 32 + t];
        qxfin[t] = s;
    }
    // ---- U A-frags for cross (Ulds stable from here on)
    short8 a2[4];
    {
        const short8* U8 = (const short8*)Ulds;
#pragma unroll
        for (int kk = 0; kk < 4; ++kk)
            a2[kk] = U8[(16 * wg + r) * 16 + ((kk * 4 + g) ^ swz)];
    }

    const float HL2E = 0.72134752044448169f;        // 0.5*log2(e)
    float rs[4] = {0.f, 0.f, 0.f, 0.f};
    short* Vlds = LT;                                // recycled

#pragma unroll
    for (int ch = 0; ch < 4; ++ch) {
        int cc0 = ch * 128;
        // ----- V chunk = C@L: wave covers center-tiles {4wg+s}, f-tile wf
#pragma unroll
        for (int s = 0; s < 4; ++s) {
            int crow = cc0 + 16 * (4 * wg + s) + r;
            f32x4 vacc = (f32x4){0.f, 0.f, 0.f, 0.f};
            short8 av[4];
#pragma unroll
            for (int kk = 0; kk < 4; ++kk)
                av[kk] = pack8(&centers[(size_t)crow * NF + kk * 32 + 8 * g]);
#pragma unroll
            for (int kk = 0; kk < 4; ++kk)
                vacc = __builtin_amdgcn_mfma_f32_16x16x32_bf16(av[kk], bb[kk], vacc, 0, 0, 0);
#pragma unroll
            for (int reg = 0; reg < 4; ++reg) {
                int row = 16 * (4 * wg + s) + 4 * g + reg;   // chunk-local center
                int col = 16 * wf + r;
                float x = vacc[reg];
                Vlds[row * NF + (((col >> 3) ^ (row & 7)) << 3) + (col & 7)] = (short)f2bf(x);
                float v = x * x;
                v += __shfl_xor(v, 1); v += __shfl_xor(v, 2);
                v += __shfl_xor(v, 4); v += __shfl_xor(v, 8);
                if (r == 0) qcw[wf * NF + row] = v;
            }
        }
        __syncthreads();
        // ----- qc reduce (waves 0-1) overlapped with cross MFMAs (all waves)
        if (t < 128) {
            float s = 0.f;
#pragma unroll
            for (int i = 0; i < 8; ++i) s += qcw[i * NF + t];
            qcfin[t] = s;
        }
        short8 bc[4];
        {
            const short8* V8 = (const short8*)Vlds;
#pragma unroll
            for (int kk = 0; kk < 4; ++kk)
                bc[kk] = V8[(16 * wf + r) * 16 + ((kk * 4 + g) ^ swz)];
        }
        f32x4 acc2 = (f32x4){0.f, 0.f, 0.f, 0.f};
#pragma unroll
        for (int kk = 0; kk < 4; ++kk)
            acc2 = __builtin_amdgcn_mfma_f32_16x16x32_bf16(a2[kk], bc[kk], acc2, 0, 0, 0);
        __syncthreads();                             // qcfin ready; Vlds reads done
        float qcl = qcfin[16 * wf + r];
#pragma unroll
        for (int reg = 0; reg < 4; ++reg) {
            int row = 16 * wg + 4 * g + reg;
            float e = (2.f * acc2[reg] - qxfin[row] - qcl) * HL2E;
            rs[reg] = fmaf(exp2f(e), wl[ch], rs[reg]);
        }
    }

    // ---- final: reduce rs over 16 center-lanes, then over 8 wf waves
#pragma unroll
    for (int reg = 0; reg < 4; ++reg) {
        float v = rs[reg];
        v += __shfl_xor(v, 1); v += __shfl_xor(v, 2);
        v += __shfl_xor(v, 4); v += __shfl_xor(v, 8);
        if (r == 0) outw[wf * 32 + 16 * wg + 4 * g + reg] = v;
    }
    __syncthreads();
    if (t < 32) {
        float s = 0.f;
#pragma unroll
        for (int i = 0; i < 8; ++i) s += outw[i * 32 + t];
        out[n0 + t] = s;
    }
}

extern "C" void kernel_launch(void* const* d_in, const int* in_sizes, int n_in,
                              void* d_out, int out_size, void* d_ws, size_t ws_size,
                              hipStream_t stream) {
    const float* X       = (const float*)d_in[0];
    const float* pe      = (const float*)d_in[1];
    const float* centers = (const float*)d_in[2];
    const float* w       = (const float*)d_in[3];
    float* out = (float*)d_out;
    (void)d_ws; (void)ws_size; (void)in_sizes; (void)n_in; (void)out_size;

    fused1_kernel<<<256, 1024, 0, stream>>>(X, pe, centers, w, out);
}

// Round 7
// 77.217 us; speedup vs baseline: 1.0015x; 1.0015x over previous
//
#include <hip/hip_runtime.h>

#define NS 8192
#define NC 512
#define NF 128

typedef short short8 __attribute__((ext_vector_type(8)));
typedef short short4v __attribute__((ext_vector_type(4)));
typedef float f32x4 __attribute__((ext_vector_type(4)));

static __device__ __forceinline__ unsigned short f2bf(float f) {
    unsigned u = __float_as_uint(f);
    return (unsigned short)((u + 0x7fffu + ((u >> 16) & 1u)) >> 16);   // RNE
}

static __device__ __forceinline__ short8 pack8(const float* p) {
    float4 v0 = *(const float4*)p;
    float4 v1 = *(const float4*)(p + 4);
    short8 o;
    o[0] = (short)f2bf(v0.x); o[1] = (short)f2bf(v0.y);
    o[2] = (short)f2bf(v0.z); o[3] = (short)f2bf(v0.w);
    o[4] = (short)f2bf(v1.x); o[5] = (short)f2bf(v1.y);
    o[6] = (short)f2bf(v1.z); o[7] = (short)f2bf(v1.w);
    return o;
}

// Swizzled short index in a [R][128] bf16 LDS tile:
//   row*128 + (((col>>3) ^ (row&7))<<3) + (col&7)

// One block = 32 samples x ALL 512 centers (4 chunks of 128). 1024 thr = 16 waves.
// __launch_bounds__(1024, 4): 4 waves/EU = 1 block/CU -> VGPR cap 128 (R6 spilled at 64).
__global__ __launch_bounds__(1024, 4) void fused1_kernel(const float* __restrict__ X,
                                                         const float* __restrict__ pe,
                                                         const float* __restrict__ centers,
                                                         const float* __restrict__ w,
                                                         float* __restrict__ out) {
    __shared__ __align__(16) short LT[NF * NF];     // 32 KB: L^T, recycled as V chunk
    __shared__ __align__(16) short Ulds[32 * NF];   // 8 KB : U = X@L bf16
    __shared__ __align__(16) short packed[8256];    // 16.5 KB packed tril(pe) bf16
    __shared__ float qxw[8 * 32];
    __shared__ float qcw[8 * NF];
    __shared__ float outw[8 * 32];
    __shared__ float qxfin[32];
    __shared__ float qcfin[NF];

    int t = threadIdx.x;
    int wv = t >> 6, lane = t & 63, g = lane >> 4, r = lane & 15;
    int wg = wv >> 3, wf = wv & 7;
    int swz = r & 7;
    int n0 = blockIdx.x * 32;

    // ---- X A-frags (fp32->bf16 in-register): rows n0 + 16wg + r
    short8 a[4];
#pragma unroll
    for (int kk = 0; kk < 4; ++kk)
        a[kk] = pack8(&X[(size_t)(n0 + 16 * wg + r) * NF + kk * 32 + 8 * g]);
    // ---- weights for this lane's 4 center columns (one per chunk)
    float wl[4];
#pragma unroll
    for (int ch = 0; ch < 4; ++ch) wl[ch] = w[ch * 128 + 16 * wf + r];

    // ---- pe -> packed LDS (coalesced), then scatter to swizzled L^T
    {
        const float4* pe4 = (const float4*)pe;
        for (int c = t; c < 2064; c += 1024) {
            float4 v = pe4[c];
            short4v o;
            o[0] = (short)f2bf(v.x); o[1] = (short)f2bf(v.y);
            o[2] = (short)f2bf(v.z); o[3] = (short)f2bf(v.w);
            ((short4v*)packed)[c] = o;
        }
    }
    __syncthreads();
    for (int idx = t; idx < NF * NF; idx += 1024) {
        int j = idx >> 7, i = idx & 127;            // LT[j][i] = L[i][j]
        short v = (j <= i) ? packed[i * (i + 1) / 2 + j] : (short)0;
        LT[j * NF + (((i >> 3) ^ (j & 7)) << 3) + (i & 7)] = v;
    }
    __syncthreads();

    // ---- B-frags of L^T for f-cols [16wf,16wf+16) (kept in regs; LT freed after)
    short8 bb[4];
    {
        const short8* L8 = (const short8*)LT;
#pragma unroll
        for (int kk = 0; kk < 4; ++kk)
            bb[kk] = L8[(16 * wf + r) * 16 + ((kk * 4 + g) ^ swz)];
    }
    // ---- U = X@L: sample-tile wg, f-tile wf
    f32x4 uacc = (f32x4){0.f, 0.f, 0.f, 0.f};
#pragma unroll
    for (int kk = 0; kk < 4; ++kk)
        uacc = __builtin_amdgcn_mfma_f32_16x16x32_bf16(a[kk], bb[kk], uacc, 0, 0, 0);
#pragma unroll
    for (int reg = 0; reg < 4; ++reg) {
        int row = 16 * wg + 4 * g + reg;            // sample-local row; col = 16wf + r
        int col = 16 * wf + r;
        float x = uacc[reg];
        Ulds[row * NF + (((col >> 3) ^ (row & 7)) << 3) + (col & 7)] = (short)f2bf(x);
        float v = x * x;
        v += __shfl_xor(v, 1); v += __shfl_xor(v, 2);
        v += __shfl_xor(v, 4); v += __shfl_xor(v, 8);
        if (r == 0) qxw[wf * 32 + row] = v;
    }
    __syncthreads();                                 // bb reads done -> LT region free
    if (t < 32) {
        float s = 0.f;
#pragma unroll
        for (int i = 0; i < 8; ++i) s += qxw[i * 32 + t];
        qxfin[t] = s;
    }
    // ---- U A-frags for cross (Ulds stable from here on)
    short8 a2[4];
    {
        const short8* U8 = (const short8*)Ulds;
#pragma unroll
        for (int kk = 0; kk < 4; ++kk)
            a2[kk] = U8[(16 * wg + r) * 16 + ((kk * 4 + g) ^ swz)];
    }

    const float HL2E = 0.72134752044448169f;        // 0.5*log2(e)
    float rs[4] = {0.f, 0.f, 0.f, 0.f};
    short* Vlds = LT;                                // recycled

#pragma unroll
    for (int ch = 0; ch < 4; ++ch) {
        int cc0 = ch * 128;
        // ----- V chunk = C@L: wave covers center-tiles {4wg+s}, f-tile wf
#pragma unroll
        for (int s = 0; s < 4; ++s) {
            int crow = cc0 + 16 * (4 * wg + s) + r;
            f32x4 vacc = (f32x4){0.f, 0.f, 0.f, 0.f};
            short8 av[4];
#pragma unroll
            for (int kk = 0; kk < 4; ++kk)
                av[kk] = pack8(&centers[(size_t)crow * NF + kk * 32 + 8 * g]);
#pragma unroll
            for (int kk = 0; kk < 4; ++kk)
                vacc = __builtin_amdgcn_mfma_f32_16x16x32_bf16(av[kk], bb[kk], vacc, 0, 0, 0);
#pragma unroll
            for (int reg = 0; reg < 4; ++reg) {
                int row = 16 * (4 * wg + s) + 4 * g + reg;   // chunk-local center
                int col = 16 * wf + r;
                float x = vacc[reg];
                Vlds[row * NF + (((col >> 3) ^ (row & 7)) << 3) + (col & 7)] = (short)f2bf(x);
                float v = x * x;
                v += __shfl_xor(v, 1); v += __shfl_xor(v, 2);
                v += __shfl_xor(v, 4); v += __shfl_xor(v, 8);
                if (r == 0) qcw[wf * NF + row] = v;
            }
        }
        __syncthreads();
        // ----- qc reduce (first 2 waves) overlapped with cross MFMAs (all waves)
        if (t < 128) {
            float s = 0.f;
#pragma unroll
            for (int i = 0; i < 8; ++i) s += qcw[i * NF + t];
            qcfin[t] = s;
        }
        short8 bc[4];
        {
            const short8* V8 = (const short8*)Vlds;
#pragma unroll
            for (int kk = 0; kk < 4; ++kk)
                bc[kk] = V8[(16 * wf + r) * 16 + ((kk * 4 + g) ^ swz)];
        }
        f32x4 acc2 = (f32x4){0.f, 0.f, 0.f, 0.f};
#pragma unroll
        for (int kk = 0; kk < 4; ++kk)
            acc2 = __builtin_amdgcn_mfma_f32_16x16x32_bf16(a2[kk], bc[kk], acc2, 0, 0, 0);
        __syncthreads();                             // qcfin ready; Vlds reads done
        float qcl = qcfin[16 * wf + r];
#pragma unroll
        for (int reg = 0; reg < 4; ++reg) {
            int row = 16 * wg + 4 * g + reg;
            float e = (2.f * acc2[reg] - qxfin[row] - qcl) * HL2E;
            rs[reg] = fmaf(exp2f(e), wl[ch], rs[reg]);
        }
    }

    // ---- final: reduce rs over 16 center-lanes, then over 8 wf waves
#pragma unroll
    for (int reg = 0; reg < 4; ++reg) {
        float v = rs[reg];
        v += __shfl_xor(v, 1); v += __shfl_xor(v, 2);
        v += __shfl_xor(v, 4); v += __shfl_xor(v, 8);
        if (r == 0) outw[wf * 32 + 16 * wg + 4 * g + reg] = v;
    }
    __syncthreads();
    if (t < 32) {
        float s = 0.f;
#pragma unroll
        for (int i = 0; i < 8; ++i) s += outw[i * 32 + t];
        out[n0 + t] = s;
    }
}

extern "C" void kernel_launch(void* const* d_in, const int* in_sizes, int n_in,
                              void* d_out, int out_size, void* d_ws, size_t ws_size,
                              hipStream_t stream) {
    const float* X       = (const float*)d_in[0];
    const float* pe      = (const float*)d_in[1];
    const float* centers = (const float*)d_in[2];
    const float* w       = (const float*)d_in[3];
    float* out = (float*)d_out;
    (void)d_ws; (void)ws_size; (void)in_sizes; (void)n_in; (void)out_size;

    fused1_kernel<<<256, 1024, 0, stream>>>(X, pe, centers, w, out);
}